// Round 7
// baseline (266.177 us; speedup 1.0000x reference)
//
#include <hip/hip_runtime.h>
#include <math.h>

#define NP 401            // tokens incl. CLS (400 patches, side=20, add=0)
#define DIM 512
#define LN_EPS 1e-5f
#define ATT_SCALE 0.125f
#define CPB_M 4096        // angle-table resolution (interp err ~2e-5 << tol)
#define TSTRIDE (CPB_M + 64)
#define PQS (401L * 1536) // layer-1 qkv partial slice stride
#define PKS (401L * 1024) // layer-2 kv partial slice stride
#define PVS (401L * 512)  // fc1 / pv / proj partial slice stride

// ---------------------------------------------------------------------------
// 64x64-tile GEMM body: 256 thr, 4x4 micro-tile, K-chunk 16. (flash/proj)
// ---------------------------------------------------------------------------
template<bool TB, typename LA, typename LB>
__device__ __forceinline__ void gemm64(
    int kBeg, int kEnd, int tid,
    float (*as)[68], float (*bs)[68], float (&acc)[4][4],
    LA&& loadA, LB&& loadB)
{
    float aR[4], bR[4];
    loadA(kBeg, aR);
    loadB(kBeg, bR);
    for (int k0 = kBeg; k0 < kEnd; k0 += 16) {
        const int arow = tid >> 2, aq = tid & 3;
        as[aq * 4 + 0][arow] = aR[0];
        as[aq * 4 + 1][arow] = aR[1];
        as[aq * 4 + 2][arow] = aR[2];
        as[aq * 4 + 3][arow] = aR[3];
        if (!TB) {
            *(float4*)&bs[tid >> 4][(tid & 15) * 4] =
                make_float4(bR[0], bR[1], bR[2], bR[3]);
        } else {
            bs[aq * 4 + 0][arow] = bR[0];
            bs[aq * 4 + 1][arow] = bR[1];
            bs[aq * 4 + 2][arow] = bR[2];
            bs[aq * 4 + 3][arow] = bR[3];
        }
        __syncthreads();
        float nA[4] = {0.f,0.f,0.f,0.f}, nB[4] = {0.f,0.f,0.f,0.f};
        if (k0 + 16 < kEnd) { loadA(k0 + 16, nA); loadB(k0 + 16, nB); }
        const int tx = tid & 15, ty = tid >> 4;
        #pragma unroll
        for (int kk = 0; kk < 16; ++kk) {
            float4 a4 = *(const float4*)&as[kk][ty * 4];
            float4 b4 = *(const float4*)&bs[kk][tx * 4];
            float av[4] = {a4.x, a4.y, a4.z, a4.w};
            float bv[4] = {b4.x, b4.y, b4.z, b4.w};
            #pragma unroll
            for (int r = 0; r < 4; ++r)
                #pragma unroll
                for (int c = 0; c < 4; ++c)
                    acc[r][c] = fmaf(av[r], bv[c], acc[r][c]);
        }
        __syncthreads();
        #pragma unroll
        for (int j = 0; j < 4; ++j) { aR[j] = nA[j]; bR[j] = nB[j]; }
    }
}

// ---------------------------------------------------------------------------
// 64x256-tile GEMM body: 256 thr, 4x16 micro-tile (cols tx*4 + 64j),
// K-chunk 16. 5 b128 LDS reads per 64 FMAs (1.6x the 64x64 ratio).
// bs[16][260]: 260 = 4 mod 32 rotates rows across banks (conflict-free).
// ---------------------------------------------------------------------------
template<typename LA, typename LB>
__device__ __forceinline__ void gemm256(
    int kBeg, int kEnd, int tid,
    float (*as)[68], float (*bs)[260], float (&acc)[4][4][4],
    LA&& loadA, LB&& loadB)
{
    float aR[4], bR[4][4];
    loadA(kBeg, aR);
    loadB(kBeg, bR);
    for (int k0 = kBeg; k0 < kEnd; k0 += 16) {
        const int arow = tid >> 2, aq = tid & 3;
        as[aq * 4 + 0][arow] = aR[0];
        as[aq * 4 + 1][arow] = aR[1];
        as[aq * 4 + 2][arow] = aR[2];
        as[aq * 4 + 3][arow] = aR[3];
        {
            const int brow = tid >> 4, bcol = (tid & 15) * 4;
            #pragma unroll
            for (int j = 0; j < 4; ++j)
                *(float4*)&bs[brow][bcol + 64 * j] =
                    make_float4(bR[j][0], bR[j][1], bR[j][2], bR[j][3]);
        }
        __syncthreads();
        float nA[4] = {0.f,0.f,0.f,0.f};
        float nB[4][4] = {};
        if (k0 + 16 < kEnd) { loadA(k0 + 16, nA); loadB(k0 + 16, nB); }
        const int tx = tid & 15, ty = tid >> 4;
        #pragma unroll
        for (int kk = 0; kk < 16; ++kk) {
            float4 a4 = *(const float4*)&as[kk][ty * 4];
            float av[4] = {a4.x, a4.y, a4.z, a4.w};
            #pragma unroll
            for (int j = 0; j < 4; ++j) {
                float4 b4 = *(const float4*)&bs[kk][tx * 4 + 64 * j];
                float bv[4] = {b4.x, b4.y, b4.z, b4.w};
                #pragma unroll
                for (int r = 0; r < 4; ++r)
                    #pragma unroll
                    for (int c = 0; c < 4; ++c)
                        acc[r][j][c] = fmaf(av[r], bv[c], acc[r][j][c]);
            }
        }
        __syncthreads();
        #pragma unroll
        for (int i = 0; i < 4; ++i) aR[i] = nA[i];
        #pragma unroll
        for (int j = 0; j < 4; ++j)
            #pragma unroll
            for (int i = 0; i < 4; ++i) bR[j][i] = nB[j][i];
    }
}

// ---------------------------------------------------------------------------
// Split-K GEMM, 64x256 tiles: P[sk] = A[:, slice] @ B[slice, :].
// K % (skN*16) == 0 by construction. grid (7, N/256, skN).
// ---------------------------------------------------------------------------
__global__ __launch_bounds__(256) void gemm_split256_kernel(
    const float* __restrict__ A, int lda,
    const float* __restrict__ B, int ldb,
    float* __restrict__ P, int ldc, long slice,
    int M, int K, int skN)
{
    __shared__ float as[16][68], bs[16][260];
    const int tid = threadIdx.x;
    const int m0 = blockIdx.x * 64, n0 = blockIdx.y * 256;
    const int sk = blockIdx.z;
    const int KS = K / skN;
    const int kBeg = sk * KS, kEnd = kBeg + KS;
    float acc[4][4][4] = {};

    auto loadA = [&](int k0, float r[4]) {
        r[0] = r[1] = r[2] = r[3] = 0.f;
        int gm = m0 + (tid >> 2);
        if (gm >= M) return;
        int gk = k0 + (tid & 3) * 4;
        float4 v = *(const float4*)(A + (long)gm * lda + gk);
        r[0]=v.x; r[1]=v.y; r[2]=v.z; r[3]=v.w;
    };
    auto loadB = [&](int k0, float r[4][4]) {
        int gk = k0 + (tid >> 4);
        const float* p = B + (long)gk * ldb + n0 + (tid & 15) * 4;
        #pragma unroll
        for (int j = 0; j < 4; ++j) {
            float4 v = *(const float4*)(p + 64 * j);
            r[j][0]=v.x; r[j][1]=v.y; r[j][2]=v.z; r[j][3]=v.w;
        }
    };
    gemm256(kBeg, kEnd, tid, as, bs, acc, loadA, loadB);

    float* C = P + (long)sk * slice;
    const int tx = tid & 15, ty = tid >> 4;
    #pragma unroll
    for (int r = 0; r < 4; ++r) {
        int m = m0 + ty * 4 + r;
        if (m >= M) continue;
        #pragma unroll
        for (int j = 0; j < 4; ++j)
            *(float4*)&C[(long)m * ldc + n0 + tx * 4 + 64 * j] =
                make_float4(acc[r][j][0], acc[r][j][1],
                            acc[r][j][2], acc[r][j][3]);
    }
}

// ---------------------------------------------------------------------------
// Fused flash attention tile (layer 1): one block = one (m-tile, kv-tile,
// head). Q/K/V read as sum of 8 qkv split-K partials + bias (L2-hot).
// QK^T via gemm64, CPB bias interp, tile-local softmax, P·V through LDS.
// grid (7, 7, 8).
// ---------------------------------------------------------------------------
__global__ __launch_bounds__(256) void flash_kernel(
    const float* __restrict__ Pq,   // 8 slices, stride PQS, ldc 1536
    const float* __restrict__ qkvb,
    const int* __restrict__ pm, const float* __restrict__ pf,
    const float* __restrict__ T,
    float* __restrict__ PO,        // (7, 401, 512) chunk partials
    float* __restrict__ Pml)       // (8, 401, 7, 2)
{
    __shared__ float as[16][68], bs[16][68];
    __shared__ float pT[64][68];   // P transposed: [key][row]
    __shared__ float vs[64][68];   // V tile: [key][dim]
    const int tid = threadIdx.x;
    const int m0 = blockIdx.x * 64, nb = blockIdx.y, h = blockIdx.z;
    const int n0 = nb * 64;
    float acc[4][4] = {};

    // V tile -> registers early (8-slice sum + bias; overlaps the QK gemm)
    float vreg[4][4];
    {
        int key = n0 + (tid >> 2);
        int d0 = (tid & 3) * 16;
        if (key <= 400) {
            long base = (long)key * 1536 + 1024 + h * 64 + d0;
            #pragma unroll
            for (int i = 0; i < 4; ++i) {
                float4 bb = *(const float4*)(qkvb + 1024 + h * 64 + d0 + i * 4);
                float r0 = bb.x, r1 = bb.y, r2 = bb.z, r3 = bb.w;
                #pragma unroll
                for (int s = 0; s < 8; ++s) {
                    float4 v = *(const float4*)(Pq + (long)s * PQS + base + i * 4);
                    r0 += v.x; r1 += v.y; r2 += v.z; r3 += v.w;
                }
                vreg[i][0] = r0; vreg[i][1] = r1;
                vreg[i][2] = r2; vreg[i][3] = r3;
            }
        } else {
            #pragma unroll
            for (int i = 0; i < 4; ++i)
                vreg[i][0] = vreg[i][1] = vreg[i][2] = vreg[i][3] = 0.f;
        }
    }

    auto loadQ = [&](int k0, float r[4]) {
        int gm = m0 + (tid >> 2);
        if (gm > 400) { r[0]=r[1]=r[2]=r[3]=0.f; return; }
        int gk = k0 + (tid & 3) * 4;
        long base = (long)gm * 1536 + h * 64 + gk;
        float4 bb = *(const float4*)(qkvb + h * 64 + gk);
        r[0] = bb.x; r[1] = bb.y; r[2] = bb.z; r[3] = bb.w;
        #pragma unroll
        for (int s = 0; s < 8; ++s) {
            float4 v = *(const float4*)(Pq + (long)s * PQS + base);
            r[0] += v.x; r[1] += v.y; r[2] += v.z; r[3] += v.w;
        }
    };
    auto loadK = [&](int k0, float r[4]) {
        int gn = n0 + (tid >> 2);
        if (gn > 400) { r[0]=r[1]=r[2]=r[3]=0.f; return; }
        int gk = k0 + (tid & 3) * 4;
        long base = (long)gn * 1536 + 512 + h * 64 + gk;
        float4 bb = *(const float4*)(qkvb + 512 + h * 64 + gk);
        r[0] = bb.x; r[1] = bb.y; r[2] = bb.z; r[3] = bb.w;
        #pragma unroll
        for (int s = 0; s < 8; ++s) {
            float4 v = *(const float4*)(Pq + (long)s * PQS + base);
            r[0] += v.x; r[1] += v.y; r[2] += v.z; r[3] += v.w;
        }
    };
    gemm64<true>(0, 64, tid, as, bs, acc, loadQ, loadK);
    // gemm64 exits right after a __syncthreads(): safe to write pT/vs now.

    // V regs -> LDS
    {
        int key = tid >> 2, d0 = (tid & 3) * 16;
        #pragma unroll
        for (int i = 0; i < 4; ++i)
            *(float4*)&vs[key][d0 + i * 4] =
                make_float4(vreg[i][0], vreg[i][1], vreg[i][2], vreg[i][3]);
    }

    // CPB bias + tile-local softmax; keep p in regs for transposed store
    const int tx = tid & 15, ty = tid >> 4;
    const float* Tt = T + (long)h * TSTRIDE;
    float p[4][4];
    #pragma unroll
    for (int r = 0; r < 4; ++r) {
        int i = m0 + ty * 4 + r;
        float sv[4];
        #pragma unroll
        for (int c = 0; c < 4; ++c) {
            int j = n0 + tx * 4 + c;
            if (i <= 400 && j <= 400) {
                int id = i * 416 + j;
                int mm = pm[id];
                float fr = pf[id];
                float t0 = Tt[mm], t1 = Tt[mm + 1];
                sv[c] = fmaf(acc[r][c], ATT_SCALE, fmaf(fr, t1 - t0, t0));
            } else {
                sv[c] = -INFINITY;
            }
        }
        float cmax = fmaxf(fmaxf(sv[0], sv[1]), fmaxf(sv[2], sv[3]));
        cmax = fmaxf(cmax, __shfl_xor(cmax, 1));
        cmax = fmaxf(cmax, __shfl_xor(cmax, 2));
        cmax = fmaxf(cmax, __shfl_xor(cmax, 4));
        cmax = fmaxf(cmax, __shfl_xor(cmax, 8));
        const bool rowok = (i <= 400);
        #pragma unroll
        for (int c = 0; c < 4; ++c)
            p[r][c] = rowok ? __expf(sv[c] - cmax) : 0.f;
        float cs = p[r][0] + p[r][1] + p[r][2] + p[r][3];
        cs += __shfl_xor(cs, 1);
        cs += __shfl_xor(cs, 2);
        cs += __shfl_xor(cs, 4);
        cs += __shfl_xor(cs, 8);
        if (tx == 0 && rowok) {
            long o = ((long)(h * 401 + i) * 7 + nb) * 2;
            Pml[o] = cmax;
            Pml[o + 1] = cs;
        }
    }
    // transposed store: pT[key][row], float4 over rows (contiguous)
    #pragma unroll
    for (int c = 0; c < 4; ++c)
        *(float4*)&pT[tx * 4 + c][ty * 4] =
            make_float4(p[0][c], p[1][c], p[2][c], p[3][c]);
    __syncthreads();

    // P·V: o[r][c] += sum_k pT[k][row] * vs[k][dim]; LDS-only operands
    float o[4][4] = {};
    #pragma unroll 16
    for (int kk = 0; kk < 64; ++kk) {
        float4 a4 = *(const float4*)&pT[kk][ty * 4];
        float4 b4 = *(const float4*)&vs[kk][tx * 4];
        float av[4] = {a4.x, a4.y, a4.z, a4.w};
        float bv[4] = {b4.x, b4.y, b4.z, b4.w};
        #pragma unroll
        for (int r = 0; r < 4; ++r)
            #pragma unroll
            for (int c = 0; c < 4; ++c)
                o[r][c] = fmaf(av[r], bv[c], o[r][c]);
    }

    float* C = PO + (long)nb * PVS;
    #pragma unroll
    for (int r = 0; r < 4; ++r) {
        int m = m0 + ty * 4 + r;
        if (m > 400) continue;
        *(float4*)&C[(long)m * 512 + h * 64 + tx * 4] =
            make_float4(o[r][0], o[r][1], o[r][2], o[r][3]);
    }
}

// ---------------------------------------------------------------------------
// proj (layer 1), split-K8 (one head per z), LSE combine of the 7 flash
// O-partials folded into the A-loader. grid (7,8,8).
// ---------------------------------------------------------------------------
__global__ __launch_bounds__(256) void proj_kernel(
    const float* __restrict__ PO, const float* __restrict__ Pml,
    const float* __restrict__ projw, float* __restrict__ Pp)
{
    __shared__ float as[16][68], bs[16][68];
    __shared__ float wls[64][8];
    const int tid = threadIdx.x;
    const int m0 = blockIdx.x * 64, n0 = blockIdx.y * 64, sk = blockIdx.z;
    const int kBeg = sk * 64, kEnd = kBeg + 64;
    float acc[4][4] = {};

    // per-row LSE merge weights for head sk
    if (tid < 64) {
        int row = m0 + tid;
        if (row <= 400) {
            const float* q = Pml + ((long)(sk * 401 + row) * 7) * 2;
            float M = -INFINITY;
            #pragma unroll
            for (int c = 0; c < 7; ++c) M = fmaxf(M, q[c * 2]);
            float D = 0.f;
            #pragma unroll
            for (int c = 0; c < 7; ++c) D += q[c * 2 + 1] * __expf(q[c * 2] - M);
            float iD = 1.f / D;
            #pragma unroll
            for (int c = 0; c < 7; ++c) wls[tid][c] = __expf(q[c * 2] - M) * iD;
        } else {
            #pragma unroll
            for (int c = 0; c < 7; ++c) wls[tid][c] = 0.f;
        }
    }
    __syncthreads();

    auto loadA = [&](int k0, float r4[4]) {
        r4[0] = r4[1] = r4[2] = r4[3] = 0.f;
        int lm = tid >> 2, gm = m0 + lm;
        if (gm > 400) return;
        int gk = k0 + (tid & 3) * 4;
        #pragma unroll
        for (int s = 0; s < 7; ++s) {
            float4 v = *(const float4*)(PO + (long)s * PVS + (long)gm * 512 + gk);
            float w = wls[lm][s];
            r4[0] = fmaf(w, v.x, r4[0]);
            r4[1] = fmaf(w, v.y, r4[1]);
            r4[2] = fmaf(w, v.z, r4[2]);
            r4[3] = fmaf(w, v.w, r4[3]);
        }
    };
    auto loadB = [&](int k0, float r[4]) {
        int gk = k0 + (tid >> 4);
        int gn = n0 + (tid & 15) * 4;
        float4 v = *(const float4*)(projw + (long)gk * 512 + gn);
        r[0]=v.x; r[1]=v.y; r[2]=v.z; r[3]=v.w;
    };
    gemm64<false>(kBeg, kEnd, tid, as, bs, acc, loadA, loadB);

    float* C = Pp + (long)sk * PVS;
    const int tx = tid & 15, ty = tid >> 4;
    #pragma unroll
    for (int r = 0; r < 4; ++r) {
        int m = m0 + ty * 4 + r;
        if (m > 400) continue;
        *(float4*)&C[(long)m * 512 + n0 + tx * 4] =
            make_float4(acc[r][0], acc[r][1], acc[r][2], acc[r][3]);
    }
}

// ---------------------------------------------------------------------------
// Per-row split-K reduce + epilogue + LayerNorm. grid 401.
// ---------------------------------------------------------------------------
__global__ __launch_bounds__(256) void rowfuse_kernel(
    const float* __restrict__ P, long slice, int skN, int rowOff,
    const float* __restrict__ bias, int doRelu,
    const float* __restrict__ resid, const float* __restrict__ cls,
    float* __restrict__ h0,
    const float* __restrict__ g, const float* __restrict__ b,
    float* __restrict__ xln)
{
    const int r = blockIdx.x, t = threadIdx.x;
    float v0, v1;
    if (cls && r == 0) {
        v0 = cls[t]; v1 = cls[t + 256];
    } else {
        const float* p = P + (long)(r - rowOff) * DIM;
        v0 = bias[t]; v1 = bias[t + 256];
        for (int k = 0; k < skN; ++k) {
            v0 += p[(long)k * slice + t];
            v1 += p[(long)k * slice + t + 256];
        }
        if (resid) {
            v0 += resid[(long)r * DIM + t];
            v1 += resid[(long)r * DIM + t + 256];
        }
        if (doRelu) { v0 = fmaxf(v0, 0.f); v1 = fmaxf(v1, 0.f); }
    }
    h0[(long)r * DIM + t] = v0;
    h0[(long)r * DIM + t + 256] = v1;

    float s = v0 + v1, sq = v0 * v0 + v1 * v1;
    #pragma unroll
    for (int off = 32; off > 0; off >>= 1) {
        s += __shfl_down(s, off);
        sq += __shfl_down(sq, off);
    }
    __shared__ float ps[4], pq[4];
    int w = t >> 6, lane = t & 63;
    if (lane == 0) { ps[w] = s; pq[w] = sq; }
    __syncthreads();
    float Sm = ps[0] + ps[1] + ps[2] + ps[3];
    float Q = pq[0] + pq[1] + pq[2] + pq[3];
    float mean = Sm * (1.f / DIM);
    float var = Q * (1.f / DIM) - mean * mean;
    float inv = rsqrtf(var + LN_EPS);
    xln[(long)r * DIM + t]       = (v0 - mean) * inv * g[t] + b[t];
    xln[(long)r * DIM + t + 256] = (v1 - mean) * inv * g[t + 256] + b[t + 256];
}

// ---------------------------------------------------------------------------
// CLS flash-decode (layer 2): grid (8 heads, 7 key-chunks of 64).
// q0 inline from xln row 0; K/V from 8 kv split-K partials + bias inline.
// Also zeroes the cls_proj completion counter (block (0,0)).
// ---------------------------------------------------------------------------
__global__ __launch_bounds__(256) void cls_decode_kernel(
    const float* __restrict__ xln, const float* __restrict__ qkvw,
    const float* __restrict__ Pkv, const float* __restrict__ qkvb,
    const int* __restrict__ pm, const float* __restrict__ pf,
    const float* __restrict__ T,
    float* __restrict__ cms, float* __restrict__ cpv,
    unsigned* __restrict__ cnt)
{
    const int h = blockIdx.x, c = blockIdx.y, tid = threadIdx.x;
    const int kBeg = c * 64;
    __shared__ float q0[64], scraw[64], p[64], red[4][64], rr[2];

    if (h == 0 && c == 0 && tid == 0) *cnt = 0u;   // init for cls_proj

    // q0[d] = sum_k xln[0][k] * Wq[k][h*64+d] + bq[h*64+d]; 4-wave k-split
    {
        int d = tid & 63, w4 = tid >> 6;
        const float* col = qkvw + h * 64 + d;
        float acc = 0.f;
        for (int k = w4 * 128; k < w4 * 128 + 128; ++k)
            acc = fmaf(xln[k], col[(long)k * 1536], acc);
        red[w4][d] = acc;
    }
    __syncthreads();
    if (tid < 64)
        q0[tid] = red[0][tid] + red[1][tid] + red[2][tid] + red[3][tid]
                  + qkvb[h * 64 + tid];
    __syncthreads();

    // scores: key k = tid>>2 (4 lanes/key, 16 dims each), shuffle-reduce
    {
        int k = tid >> 2, q = tid & 3;
        int j = kBeg + k;
        float dot = 0.f;
        if (j < NP) {
            long base = (long)j * 1024 + h * 64 + q * 16;   // K cols 0..512
            #pragma unroll
            for (int d = 0; d < 16; d += 4) {
                float4 x = *(const float4*)(qkvb + 512 + h * 64 + q * 16 + d);
                #pragma unroll
                for (int s = 0; s < 8; ++s) {
                    float4 v = *(const float4*)(Pkv + (long)s * PKS + base + d);
                    x.x += v.x; x.y += v.y; x.z += v.z; x.w += v.w;
                }
                float4 qq = *(const float4*)(q0 + q * 16 + d);
                dot = fmaf(qq.x, x.x, dot);
                dot = fmaf(qq.y, x.y, dot);
                dot = fmaf(qq.z, x.z, dot);
                dot = fmaf(qq.w, x.w, dot);
            }
        }
        dot += __shfl_down(dot, 2);
        dot += __shfl_down(dot, 1);
        if (q == 0) scraw[k] = dot;
    }
    __syncthreads();

    // bias + local softmax on wave 0
    if (tid < 64) {
        int j = kBeg + tid;
        float s;
        if (j < NP) {
            int mm = pm[j];                   // row 0 of pair map
            float fr = pf[j];
            const float* Tt = T + (long)h * TSTRIDE;
            float t0 = Tt[mm], t1 = Tt[mm + 1];
            s = fmaf(scraw[tid], ATT_SCALE, fmaf(fr, t1 - t0, t0));
        } else {
            s = -INFINITY;
        }
        float m = s;
        #pragma unroll
        for (int off = 32; off > 0; off >>= 1)
            m = fmaxf(m, __shfl_xor(m, off));
        float e = (j < NP) ? __expf(s - m) : 0.f;
        float sum = e;
        #pragma unroll
        for (int off = 32; off > 0; off >>= 1)
            sum += __shfl_xor(sum, off);
        p[tid] = e;
        if (tid == 0) { rr[0] = m; rr[1] = sum; }
    }
    __syncthreads();

    // partial PV: d = lane, wave w handles keys k ≡ w (mod 4)
    {
        int w = tid >> 6, d = tid & 63;
        float vb = qkvb[1024 + h * 64 + d];
        float acc = 0.f;
        for (int k = w; k < 64; k += 4) {
            int j = kBeg + k;
            if (j >= NP) break;
            long o = (long)j * 1024 + 512 + h * 64 + d;     // V cols 512..1024
            float v = vb;
            #pragma unroll
            for (int s = 0; s < 8; ++s) v += Pkv[(long)s * PKS + o];
            acc = fmaf(p[k], v, acc);
        }
        red[w][d] = acc;
    }
    __syncthreads();
    if (tid < 64) {
        cpv[((long)h * 7 + c) * 64 + tid] =
            red[0][tid] + red[1][tid] + red[2][tid] + red[3][tid];
        if (tid == 0) {
            cms[(h * 7 + c) * 2 + 0] = rr[0];
            cms[(h * 7 + c) * 2 + 1] = rr[1];
        }
    }
}

// ---------------------------------------------------------------------------
// CLS proj (inlined LSE combine) + last-block fused residual+LN+fc2 -> out.
// grid 8 x 256 thr.
// ---------------------------------------------------------------------------
__global__ __launch_bounds__(256) void cls_proj_kernel(
    const float* __restrict__ cms, const float* __restrict__ cpv,
    const float* __restrict__ projw, const float* __restrict__ projb,
    float* __restrict__ proj0,
    const float* __restrict__ h0,
    const float* __restrict__ g, const float* __restrict__ b,
    const float* __restrict__ fc2w, const float* __restrict__ fc2b,
    float* __restrict__ out, unsigned* __restrict__ cnt)
{
    __shared__ float av[512], red[4][64];
    __shared__ int isLast;
    const int bk = blockIdx.x, tid = threadIdx.x;
    for (int d = tid; d < 512; d += 256) {
        int h = d >> 6, dd = d & 63;
        float M = -INFINITY;
        #pragma unroll
        for (int c = 0; c < 7; ++c)
            M = fmaxf(M, cms[(h * 7 + c) * 2]);
        float Sx = 0.f, acc = 0.f;
        #pragma unroll
        for (int c = 0; c < 7; ++c) {
            float e = __expf(cms[(h * 7 + c) * 2] - M);
            Sx += cms[(h * 7 + c) * 2 + 1] * e;
            acc += cpv[((long)h * 7 + c) * 64 + dd] * e;
        }
        av[d] = acc / Sx;
    }
    __syncthreads();
    int gg = tid >> 6, n = bk * 64 + (tid & 63);
    float acc = 0.f;
    for (int k = gg * 128; k < gg * 128 + 128; ++k)
        acc = fmaf(av[k], projw[(long)k * 512 + n], acc);
    red[gg][tid & 63] = acc;
    __syncthreads();
    if (tid < 64)
        proj0[bk * 64 + tid] = red[0][tid] + red[1][tid] + red[2][tid]
                               + red[3][tid] + projb[bk * 64 + tid];

    // last-block: residual + LN + fc2 -> out
    __threadfence();
    if (tid == 0) isLast = (atomicAdd(cnt, 1u) == 7u);
    __syncthreads();
    if (!isLast) return;
    __threadfence();

    const int t = tid;
    float v0 = h0[t] + proj0[t];
    float v1 = h0[t + 256] + proj0[t + 256];
    float s = v0 + v1, sq = v0 * v0 + v1 * v1;
    #pragma unroll
    for (int off = 32; off > 0; off >>= 1) {
        s += __shfl_down(s, off);
        sq += __shfl_down(sq, off);
    }
    __shared__ float ps[4], pq[4], pc0[4], pc1[4];
    int w = t >> 6, lane = t & 63;
    if (lane == 0) { ps[w] = s; pq[w] = sq; }
    __syncthreads();
    float Sm = ps[0] + ps[1] + ps[2] + ps[3];
    float Q = pq[0] + pq[1] + pq[2] + pq[3];
    float mean = Sm * (1.f / DIM);
    float var = Q * (1.f / DIM) - mean * mean;
    float inv = rsqrtf(var + LN_EPS);
    float n0 = (v0 - mean) * inv * g[t] + b[t];
    float n1 = (v1 - mean) * inv * g[t + 256] + b[t + 256];
    float c0 = n0 * fc2w[t * 2]     + n1 * fc2w[(t + 256) * 2];
    float c1 = n0 * fc2w[t * 2 + 1] + n1 * fc2w[(t + 256) * 2 + 1];
    #pragma unroll
    for (int off = 32; off > 0; off >>= 1) {
        c0 += __shfl_down(c0, off);
        c1 += __shfl_down(c1, off);
    }
    if (lane == 0) { pc0[w] = c0; pc1[w] = c1; }
    __syncthreads();
    if (t == 0) {
        out[0] = pc0[0] + pc0[1] + pc0[2] + pc0[3] + fc2b[0];
        out[1] = pc1[0] + pc1[1] + pc1[2] + pc1[3] + fc2b[1];
    }
}

// ---------------------------------------------------------------------------
// Mega init: [0,224) fc1 split-K16 64x256 tiles -> Pp; [224,354) CPB angle
// tables; [354,983) pair -> (angle idx, frac).
// ---------------------------------------------------------------------------
__global__ __launch_bounds__(256) void mega_kernel(
    const float* __restrict__ hin, const float* __restrict__ fc1_w,
    const float* __restrict__ w1_0, const float* __restrict__ b1_0,
    const float* __restrict__ w2_0, const float* __restrict__ b2_0,
    const float* __restrict__ w1_1, const float* __restrict__ b1_1,
    const float* __restrict__ w2_1, const float* __restrict__ b2_1,
    const float* __restrict__ coords,
    float* __restrict__ Pp, float* __restrict__ T,
    int* __restrict__ pm, float* __restrict__ pf)
{
    __shared__ float smem[5248];
    float (*as)[68]  = (float(*)[68])smem;
    float (*bs)[260] = (float(*)[260])(smem + 1088);
    float (*red)[64][8] = (float(*)[64][8])smem;
    const int bid = blockIdx.x, tid = threadIdx.x;

    if (bid < 224) {
        int sk = bid / 14, rem = bid % 14;
        int m0 = (rem % 7) * 64, n0 = (rem / 7) * 256;
        int kBeg = sk * 64, kEnd = kBeg + 64;   // 16 x 64 = full K=1024
        float acc[4][4][4] = {};
        auto loadA = [&](int k0, float r[4]) {
            r[0]=r[1]=r[2]=r[3]=0.f;
            int gm = m0 + (tid >> 2);
            if (gm >= 400) return;
            int gk = k0 + (tid & 3) * 4;
            float4 v = *(const float4*)(hin + (long)gm * 1024 + gk);
            r[0]=v.x; r[1]=v.y; r[2]=v.z; r[3]=v.w;
        };
        auto loadB = [&](int k0, float r[4][4]) {
            int gk = k0 + (tid >> 4);
            const float* p = fc1_w + (long)gk * 512 + n0 + (tid & 15) * 4;
            #pragma unroll
            for (int j = 0; j < 4; ++j) {
                float4 v = *(const float4*)(p + 64 * j);
                r[j][0]=v.x; r[j][1]=v.y; r[j][2]=v.z; r[j][3]=v.w;
            }
        };
        gemm256(kBeg, kEnd, tid, as, bs, acc, loadA, loadB);
        float* C = Pp + (long)sk * PVS;
        const int tx = tid & 15, ty = tid >> 4;
        #pragma unroll
        for (int r = 0; r < 4; ++r) {
            int m = m0 + ty * 4 + r;
            if (m >= 400) continue;
            #pragma unroll
            for (int j = 0; j < 4; ++j)
                *(float4*)&C[(long)m * 512 + n0 + tx * 4 + 64 * j] =
                    make_float4(acc[r][j][0], acc[r][j][1],
                                acc[r][j][2], acc[r][j][3]);
        }
    } else if (bid < 354) {
        int tb = bid - 224;
        int z = tb / 65, ab = tb % 65;
        const float* w1 = z ? w1_1 : w1_0;
        const float* b1 = z ? b1_1 : b1_0;
        const float* w2 = z ? w2_1 : w2_0;
        const float* b2 = z ? b2_1 : b2_0;
        const int lane = tid & 63, wv = tid >> 6;
        float ca = 0.f, sa = 0.f;
        if (ab != 64) {
            float th = fmaf((float)(ab * 64 + lane),
                            (float)(2.0 * M_PI / CPB_M), -(float)M_PI);
            sincosf(th, &sa, &ca);
        } else if (lane == 0) {
            sincosf((float)M_PI, &sa, &ca);  // wrap row; lanes>0 zero-vec
        }
        float a8[8] = {};
        const int kbeg = wv * 128;
        #pragma unroll 4
        for (int k = kbeg; k < kbeg + 128; ++k) {
            float hk = fmaxf(fmaf(ca, w1[k],
                                  fmaf(sa, w1[512 + k], b1[k])), 0.f);
            #pragma unroll
            for (int h2 = 0; h2 < 8; ++h2)
                a8[h2] = fmaf(hk, w2[k * 8 + h2], a8[h2]);
        }
        #pragma unroll
        for (int h2 = 0; h2 < 8; ++h2) red[wv][lane][h2] = a8[h2];
        __syncthreads();
        if (tid < 64) {
            int aidx = ab * 64 + tid;
            if (aidx <= CPB_M + 1) {
                #pragma unroll
                for (int h2 = 0; h2 < 8; ++h2)
                    T[(long)(z * 8 + h2) * TSTRIDE + aidx] =
                        red[0][tid][h2] + red[1][tid][h2] +
                        red[2][tid][h2] + red[3][tid][h2] + b2[h2];
            }
        }
    } else {
        int p = (bid - 354) * 256 + tid;
        if (p < NP * NP) {
            int i = p / NP, j = p - i * NP;
            float xi = (i == 0) ? 0.f : coords[(i - 1) * 2];
            float yi = (i == 0) ? 0.f : coords[(i - 1) * 2 + 1];
            float xj = (j == 0) ? 0.f : coords[(j - 1) * 2];
            float yj = (j == 0) ? 0.f : coords[(j - 1) * 2 + 1];
            float rx = xi - xj, ry = yi - yj;
            int mm; float fr;
            if (rx == 0.f && ry == 0.f) {
                mm = CPB_M + 1; fr = 0.f;
            } else {
                float x = (atan2f(ry, rx) + 3.14159265358979f)
                          * (float)(CPB_M / (2.0 * M_PI));
                int mi = (int)x;
                fr = x - (float)mi;
                mm = (mi >= CPB_M) ? mi - CPB_M : mi;
            }
            pm[i * 416 + j] = mm;
            pf[i * 416 + j] = fr;
        }
    }
}

// ---------------------------------------------------------------------------
extern "C" void kernel_launch(void* const* d_in, const int* in_sizes, int n_in,
                              void* d_out, int out_size, void* d_ws, size_t ws_size,
                              hipStream_t stream)
{
    const float* coords = (const float*)d_in[1];
    float* ws = (float*)d_ws;
    float* h0   = ws;                    ws += 401L * 512;
    float* xln  = ws;                    ws += 401L * 512;
    float* PO   = ws;                    ws += 7L * PVS;   // flash O-partials
    float* T    = ws;                    ws += 16L * TSTRIDE;
    int*   pm   = (int*)ws;              ws += 401L * 416;
    float* pf   = ws;                    ws += 401L * 416;
    float* Pq   = ws;                    ws += 8L * PQS;   // qkv / l2-kv partials
    float* Pp   = ws;                    ws += 16L * PVS;  // fc1(K16)/proj(K8)
    float* proj0 = ws;                   ws += 512;
    float* cms  = ws;                    ws += 8L * 7 * 2;
    float* cpv  = ws;                    ws += 8L * 7 * 64;
    float* Pml  = ws;                    ws += 8L * 401 * 7 * 2;
    unsigned* cnt = (unsigned*)ws;       ws += 16;

    // phase 0: fc1 (split-K16, 64x256) + CPB angle tables + pair->angle map
    mega_kernel<<<983, 256, 0, stream>>>(
        (const float*)d_in[0], (const float*)d_in[2],
        (const float*)d_in[7],  (const float*)d_in[8],
        (const float*)d_in[9],  (const float*)d_in[10],
        (const float*)d_in[17], (const float*)d_in[18],
        (const float*)d_in[19], (const float*)d_in[20],
        coords, Pp, T, pm, pf);

    // fc1 reduce + relu + cls + LN(l1) -> h0, xln
    rowfuse_kernel<<<401, 256, 0, stream>>>(
        Pp, PVS, 16, 1, (const float*)d_in[3], 1, nullptr,
        (const float*)d_in[4], h0,
        (const float*)d_in[5], (const float*)d_in[6], xln);

    // -------- layer 1: split-K8 64x256 qkv, flash folds sum+bias ------
    gemm_split256_kernel<<<dim3(7, 6, 8), 256, 0, stream>>>(
        xln, 512, (const float*)d_in[11], 1536, Pq, 1536, PQS,
        401, 512, 8);
    flash_kernel<<<dim3(7, 7, 8), 256, 0, stream>>>(
        Pq, (const float*)d_in[12], pm, pf, T, PO, Pml);
    proj_kernel<<<dim3(7, 8, 8), 256, 0, stream>>>(
        PO, Pml, (const float*)d_in[13], Pp);
    rowfuse_kernel<<<401, 256, 0, stream>>>(
        Pp, PVS, 8, 0, (const float*)d_in[14], 0, h0, nullptr, h0,
        (const float*)d_in[15], (const float*)d_in[16], xln);

    // -------- layer 2: split-K8 64x256 K,V, CLS flash-decode ----------
    gemm_split256_kernel<<<dim3(7, 4, 8), 256, 0, stream>>>(
        xln, 512, (const float*)d_in[21] + 512, 1536, Pq, 1024, PKS,
        401, 512, 8);
    cls_decode_kernel<<<dim3(8, 7), 256, 0, stream>>>(
        xln, (const float*)d_in[21], Pq, (const float*)d_in[22],
        pm, pf, T + 8L * TSTRIDE, cms, cpv, cnt);
    cls_proj_kernel<<<8, 256, 0, stream>>>(
        cms, cpv, (const float*)d_in[23], (const float*)d_in[24], proj0,
        h0, (const float*)d_in[25], (const float*)d_in[26],
        (const float*)d_in[27], (const float*)d_in[28], (float*)d_out, cnt);
}

// Round 8
// 238.049 us; speedup vs baseline: 1.1182x; 1.1182x over previous
//
#include <hip/hip_runtime.h>
#include <math.h>

#define NP 401            // tokens incl. CLS (400 patches, side=20, add=0)
#define DIM 512
#define LN_EPS 1e-5f
#define ATT_SCALE 0.125f
#define CPB_M 4096        // angle-table resolution (interp err ~2e-5 << tol)
#define TSTRIDE (CPB_M + 64)
#define PQS (401L * 1536) // layer-1 qkv partial slice stride
#define PKS (401L * 1024) // layer-2 kv partial slice stride
#define PVS (401L * 512)  // fc1 / pv / proj partial slice stride

// ---------------------------------------------------------------------------
// 64x64-tile GEMM body: 256 thr, 4x4 micro-tile, K-chunk 16. (flash/proj/kv)
// ---------------------------------------------------------------------------
template<bool TB, typename LA, typename LB>
__device__ __forceinline__ void gemm64(
    int kBeg, int kEnd, int tid,
    float (*as)[68], float (*bs)[68], float (&acc)[4][4],
    LA&& loadA, LB&& loadB)
{
    float aR[4], bR[4];
    loadA(kBeg, aR);
    loadB(kBeg, bR);
    for (int k0 = kBeg; k0 < kEnd; k0 += 16) {
        const int arow = tid >> 2, aq = tid & 3;
        as[aq * 4 + 0][arow] = aR[0];
        as[aq * 4 + 1][arow] = aR[1];
        as[aq * 4 + 2][arow] = aR[2];
        as[aq * 4 + 3][arow] = aR[3];
        if (!TB) {
            *(float4*)&bs[tid >> 4][(tid & 15) * 4] =
                make_float4(bR[0], bR[1], bR[2], bR[3]);
        } else {
            bs[aq * 4 + 0][arow] = bR[0];
            bs[aq * 4 + 1][arow] = bR[1];
            bs[aq * 4 + 2][arow] = bR[2];
            bs[aq * 4 + 3][arow] = bR[3];
        }
        __syncthreads();
        float nA[4] = {0.f,0.f,0.f,0.f}, nB[4] = {0.f,0.f,0.f,0.f};
        if (k0 + 16 < kEnd) { loadA(k0 + 16, nA); loadB(k0 + 16, nB); }
        const int tx = tid & 15, ty = tid >> 4;
        #pragma unroll
        for (int kk = 0; kk < 16; ++kk) {
            float4 a4 = *(const float4*)&as[kk][ty * 4];
            float4 b4 = *(const float4*)&bs[kk][tx * 4];
            float av[4] = {a4.x, a4.y, a4.z, a4.w};
            float bv[4] = {b4.x, b4.y, b4.z, b4.w};
            #pragma unroll
            for (int r = 0; r < 4; ++r)
                #pragma unroll
                for (int c = 0; c < 4; ++c)
                    acc[r][c] = fmaf(av[r], bv[c], acc[r][c]);
        }
        __syncthreads();
        #pragma unroll
        for (int j = 0; j < 4; ++j) { aR[j] = nA[j]; bR[j] = nB[j]; }
    }
}

// ---------------------------------------------------------------------------
// 64x128-tile GEMM body: 256 thr, 4x8 micro-tile (cols tx*4 and tx*4+64),
// K-chunk 16. 3 b128 LDS reads per 32 FMAs (1.8x the 64x64 ratio).
// ---------------------------------------------------------------------------
template<typename LA, typename LB>
__device__ __forceinline__ void gemm128(
    int kBeg, int kEnd, int tid,
    float (*as)[68], float (*bs)[132], float (&acc)[4][2][4],
    LA&& loadA, LB&& loadB)
{
    float aR[4], bR[2][4];
    loadA(kBeg, aR);
    loadB(kBeg, bR);
    for (int k0 = kBeg; k0 < kEnd; k0 += 16) {
        const int arow = tid >> 2, aq = tid & 3;
        as[aq * 4 + 0][arow] = aR[0];
        as[aq * 4 + 1][arow] = aR[1];
        as[aq * 4 + 2][arow] = aR[2];
        as[aq * 4 + 3][arow] = aR[3];
        {
            const int brow = tid >> 4, bcol = (tid & 15) * 4;
            *(float4*)&bs[brow][bcol] =
                make_float4(bR[0][0], bR[0][1], bR[0][2], bR[0][3]);
            *(float4*)&bs[brow][bcol + 64] =
                make_float4(bR[1][0], bR[1][1], bR[1][2], bR[1][3]);
        }
        __syncthreads();
        float nA[4] = {0.f,0.f,0.f,0.f};
        float nB[2][4] = {};
        if (k0 + 16 < kEnd) { loadA(k0 + 16, nA); loadB(k0 + 16, nB); }
        const int tx = tid & 15, ty = tid >> 4;
        #pragma unroll
        for (int kk = 0; kk < 16; ++kk) {
            float4 a4 = *(const float4*)&as[kk][ty * 4];
            float av[4] = {a4.x, a4.y, a4.z, a4.w};
            #pragma unroll
            for (int j = 0; j < 2; ++j) {
                float4 b4 = *(const float4*)&bs[kk][tx * 4 + 64 * j];
                float bv[4] = {b4.x, b4.y, b4.z, b4.w};
                #pragma unroll
                for (int r = 0; r < 4; ++r)
                    #pragma unroll
                    for (int c = 0; c < 4; ++c)
                        acc[r][j][c] = fmaf(av[r], bv[c], acc[r][j][c]);
            }
        }
        __syncthreads();
        #pragma unroll
        for (int i = 0; i < 4; ++i) aR[i] = nA[i];
        #pragma unroll
        for (int j = 0; j < 2; ++j)
            #pragma unroll
            for (int i = 0; i < 4; ++i) bR[j][i] = nB[j][i];
    }
}

// ---------------------------------------------------------------------------
// Split-K GEMM, 64x128 tiles: P[sk] = A[:, slice] @ B[slice, :].
// grid (7, N/128, skN). K % (skN*16) == 0.
// ---------------------------------------------------------------------------
__global__ __launch_bounds__(256) void gemm_split128_kernel(
    const float* __restrict__ A, int lda,
    const float* __restrict__ B, int ldb,
    float* __restrict__ P, int ldc, long slice,
    int M, int K, int skN)
{
    __shared__ float as[16][68], bs[16][132];
    const int tid = threadIdx.x;
    const int m0 = blockIdx.x * 64, n0 = blockIdx.y * 128;
    const int sk = blockIdx.z;
    const int KS = K / skN;
    const int kBeg = sk * KS, kEnd = kBeg + KS;
    float acc[4][2][4] = {};

    auto loadA = [&](int k0, float r[4]) {
        r[0] = r[1] = r[2] = r[3] = 0.f;
        int gm = m0 + (tid >> 2);
        if (gm >= M) return;
        int gk = k0 + (tid & 3) * 4;
        float4 v = *(const float4*)(A + (long)gm * lda + gk);
        r[0]=v.x; r[1]=v.y; r[2]=v.z; r[3]=v.w;
    };
    auto loadB = [&](int k0, float r[2][4]) {
        int gk = k0 + (tid >> 4);
        const float* p = B + (long)gk * ldb + n0 + (tid & 15) * 4;
        #pragma unroll
        for (int j = 0; j < 2; ++j) {
            float4 v = *(const float4*)(p + 64 * j);
            r[j][0]=v.x; r[j][1]=v.y; r[j][2]=v.z; r[j][3]=v.w;
        }
    };
    gemm128(kBeg, kEnd, tid, as, bs, acc, loadA, loadB);

    float* C = P + (long)sk * slice;
    const int tx = tid & 15, ty = tid >> 4;
    #pragma unroll
    for (int r = 0; r < 4; ++r) {
        int m = m0 + ty * 4 + r;
        if (m >= M) continue;
        #pragma unroll
        for (int j = 0; j < 2; ++j)
            *(float4*)&C[(long)m * ldc + n0 + tx * 4 + 64 * j] =
                make_float4(acc[r][j][0], acc[r][j][1],
                            acc[r][j][2], acc[r][j][3]);
    }
}

// ---------------------------------------------------------------------------
// Generic split-K GEMM, 64x64 tiles (layer-2 kv). grid (7, N/64, skN).
// ---------------------------------------------------------------------------
__global__ __launch_bounds__(256) void gemm_split_kernel(
    const float* __restrict__ A, int lda,
    const float* __restrict__ B, int ldb,
    float* __restrict__ P, int ldc, long slice,
    int M, int K, int skN)
{
    __shared__ float as[16][68], bs[16][68];
    const int tid = threadIdx.x;
    const int m0 = blockIdx.x * 64, n0 = blockIdx.y * 64;
    const int sk = blockIdx.z;
    const int KS = K / skN;
    const int kBeg = sk * KS, kEnd = kBeg + KS;
    float acc[4][4] = {};

    auto loadA = [&](int k0, float r[4]) {
        r[0] = r[1] = r[2] = r[3] = 0.f;
        int gm = m0 + (tid >> 2);
        if (gm >= M) return;
        int gk = k0 + (tid & 3) * 4;
        float4 v = *(const float4*)(A + (long)gm * lda + gk);
        r[0]=v.x; r[1]=v.y; r[2]=v.z; r[3]=v.w;
    };
    auto loadB = [&](int k0, float r[4]) {
        int gk = k0 + (tid >> 4);
        int gn = n0 + (tid & 15) * 4;
        float4 v = *(const float4*)(B + (long)gk * ldb + gn);
        r[0]=v.x; r[1]=v.y; r[2]=v.z; r[3]=v.w;
    };
    gemm64<false>(kBeg, kEnd, tid, as, bs, acc, loadA, loadB);

    float* C = P + (long)sk * slice;
    const int tx = tid & 15, ty = tid >> 4;
    #pragma unroll
    for (int r = 0; r < 4; ++r) {
        int m = m0 + ty * 4 + r;
        if (m >= M) continue;
        *(float4*)&C[(long)m * ldc + n0 + tx * 4] =
            make_float4(acc[r][0], acc[r][1], acc[r][2], acc[r][3]);
    }
}

// ---------------------------------------------------------------------------
// Fused flash attention tile (layer 1): Q/K/V read as sum of 2 qkv split-K
// partials + bias. QK^T via gemm64, CPB bias interp, tile-local softmax,
// P·V through LDS. grid (7, 7, 8).
// ---------------------------------------------------------------------------
__global__ __launch_bounds__(256) void flash_kernel(
    const float* __restrict__ Pq,   // 2 slices, stride PQS, ldc 1536
    const float* __restrict__ qkvb,
    const int* __restrict__ pm, const float* __restrict__ pf,
    const float* __restrict__ T,
    float* __restrict__ PO,        // (7, 401, 512) chunk partials
    float* __restrict__ Pml)       // (8, 401, 7, 2)
{
    __shared__ float as[16][68], bs[16][68];
    __shared__ float pT[64][68];   // P transposed: [key][row]
    __shared__ float vs[64][68];   // V tile: [key][dim]
    const int tid = threadIdx.x;
    const int m0 = blockIdx.x * 64, nb = blockIdx.y, h = blockIdx.z;
    const int n0 = nb * 64;
    float acc[4][4] = {};

    // V tile -> registers early (2-slice sum + bias; overlaps the QK gemm)
    float vreg[4][4];
    {
        int key = n0 + (tid >> 2);
        int d0 = (tid & 3) * 16;
        if (key <= 400) {
            long base = (long)key * 1536 + 1024 + h * 64 + d0;
            #pragma unroll
            for (int i = 0; i < 4; ++i) {
                float4 v0 = *(const float4*)(Pq + base + i * 4);
                float4 v1 = *(const float4*)(Pq + PQS + base + i * 4);
                float4 bb = *(const float4*)(qkvb + 1024 + h * 64 + d0 + i * 4);
                vreg[i][0] = v0.x + v1.x + bb.x;
                vreg[i][1] = v0.y + v1.y + bb.y;
                vreg[i][2] = v0.z + v1.z + bb.z;
                vreg[i][3] = v0.w + v1.w + bb.w;
            }
        } else {
            #pragma unroll
            for (int i = 0; i < 4; ++i)
                vreg[i][0] = vreg[i][1] = vreg[i][2] = vreg[i][3] = 0.f;
        }
    }

    auto loadQ = [&](int k0, float r[4]) {
        int gm = m0 + (tid >> 2);
        if (gm > 400) { r[0]=r[1]=r[2]=r[3]=0.f; return; }
        int gk = k0 + (tid & 3) * 4;
        long base = (long)gm * 1536 + h * 64 + gk;
        float4 v0 = *(const float4*)(Pq + base);
        float4 v1 = *(const float4*)(Pq + PQS + base);
        float4 bb = *(const float4*)(qkvb + h * 64 + gk);
        r[0] = v0.x + v1.x + bb.x;
        r[1] = v0.y + v1.y + bb.y;
        r[2] = v0.z + v1.z + bb.z;
        r[3] = v0.w + v1.w + bb.w;
    };
    auto loadK = [&](int k0, float r[4]) {
        int gn = n0 + (tid >> 2);
        if (gn > 400) { r[0]=r[1]=r[2]=r[3]=0.f; return; }
        int gk = k0 + (tid & 3) * 4;
        long base = (long)gn * 1536 + 512 + h * 64 + gk;
        float4 v0 = *(const float4*)(Pq + base);
        float4 v1 = *(const float4*)(Pq + PQS + base);
        float4 bb = *(const float4*)(qkvb + 512 + h * 64 + gk);
        r[0] = v0.x + v1.x + bb.x;
        r[1] = v0.y + v1.y + bb.y;
        r[2] = v0.z + v1.z + bb.z;
        r[3] = v0.w + v1.w + bb.w;
    };
    gemm64<true>(0, 64, tid, as, bs, acc, loadQ, loadK);
    // gemm64 exits right after a __syncthreads(): safe to write pT/vs now.

    // V regs -> LDS
    {
        int key = tid >> 2, d0 = (tid & 3) * 16;
        #pragma unroll
        for (int i = 0; i < 4; ++i)
            *(float4*)&vs[key][d0 + i * 4] =
                make_float4(vreg[i][0], vreg[i][1], vreg[i][2], vreg[i][3]);
    }

    // CPB bias + tile-local softmax; keep p in regs for transposed store
    const int tx = tid & 15, ty = tid >> 4;
    const float* Tt = T + (long)h * TSTRIDE;
    float p[4][4];
    #pragma unroll
    for (int r = 0; r < 4; ++r) {
        int i = m0 + ty * 4 + r;
        float sv[4];
        #pragma unroll
        for (int c = 0; c < 4; ++c) {
            int j = n0 + tx * 4 + c;
            if (i <= 400 && j <= 400) {
                int id = i * 416 + j;
                int mm = pm[id];
                float fr = pf[id];
                float t0 = Tt[mm], t1 = Tt[mm + 1];
                sv[c] = fmaf(acc[r][c], ATT_SCALE, fmaf(fr, t1 - t0, t0));
            } else {
                sv[c] = -INFINITY;
            }
        }
        float cmax = fmaxf(fmaxf(sv[0], sv[1]), fmaxf(sv[2], sv[3]));
        cmax = fmaxf(cmax, __shfl_xor(cmax, 1));
        cmax = fmaxf(cmax, __shfl_xor(cmax, 2));
        cmax = fmaxf(cmax, __shfl_xor(cmax, 4));
        cmax = fmaxf(cmax, __shfl_xor(cmax, 8));
        const bool rowok = (i <= 400);
        #pragma unroll
        for (int c = 0; c < 4; ++c)
            p[r][c] = rowok ? __expf(sv[c] - cmax) : 0.f;
        float cs = p[r][0] + p[r][1] + p[r][2] + p[r][3];
        cs += __shfl_xor(cs, 1);
        cs += __shfl_xor(cs, 2);
        cs += __shfl_xor(cs, 4);
        cs += __shfl_xor(cs, 8);
        if (tx == 0 && rowok) {
            long o = ((long)(h * 401 + i) * 7 + nb) * 2;
            Pml[o] = cmax;
            Pml[o + 1] = cs;
        }
    }
    // transposed store: pT[key][row], float4 over rows (contiguous)
    #pragma unroll
    for (int c = 0; c < 4; ++c)
        *(float4*)&pT[tx * 4 + c][ty * 4] =
            make_float4(p[0][c], p[1][c], p[2][c], p[3][c]);
    __syncthreads();

    // P·V: o[r][c] += sum_k pT[k][row] * vs[k][dim]; LDS-only operands
    float o[4][4] = {};
    #pragma unroll 16
    for (int kk = 0; kk < 64; ++kk) {
        float4 a4 = *(const float4*)&pT[kk][ty * 4];
        float4 b4 = *(const float4*)&vs[kk][tx * 4];
        float av[4] = {a4.x, a4.y, a4.z, a4.w};
        float bv[4] = {b4.x, b4.y, b4.z, b4.w};
        #pragma unroll
        for (int r = 0; r < 4; ++r)
            #pragma unroll
            for (int c = 0; c < 4; ++c)
                o[r][c] = fmaf(av[r], bv[c], o[r][c]);
    }

    float* C = PO + (long)nb * PVS;
    #pragma unroll
    for (int r = 0; r < 4; ++r) {
        int m = m0 + ty * 4 + r;
        if (m > 400) continue;
        *(float4*)&C[(long)m * 512 + h * 64 + tx * 4] =
            make_float4(o[r][0], o[r][1], o[r][2], o[r][3]);
    }
}

// ---------------------------------------------------------------------------
// LSE combine: att[r][d] = sum_s w[r,h(d)][s] * PO[s][r][d] (normalized).
// grid 401 x 256 thr, 2 elems/thread. Reads 5.7 MB once (vs 58 MB fold-7).
// ---------------------------------------------------------------------------
__global__ __launch_bounds__(256) void combine_kernel(
    const float* __restrict__ PO, const float* __restrict__ Pml,
    float* __restrict__ att)
{
    const int r = blockIdx.x, t = threadIdx.x;
    #pragma unroll
    for (int half = 0; half < 2; ++half) {
        int d = t + half * 256;
        int h = d >> 6;
        const float* q = Pml + ((long)(h * 401 + r) * 7) * 2;
        float M = -INFINITY;
        #pragma unroll
        for (int c = 0; c < 7; ++c) M = fmaxf(M, q[c * 2]);
        float D = 0.f;
        #pragma unroll
        for (int c = 0; c < 7; ++c) D += q[c * 2 + 1] * __expf(q[c * 2] - M);
        float acc = 0.f;
        #pragma unroll
        for (int s = 0; s < 7; ++s)
            acc = fmaf(__expf(q[s * 2] - M),
                       PO[(long)s * PVS + (long)r * 512 + d], acc);
        att[(long)r * 512 + d] = acc / D;
    }
}

// ---------------------------------------------------------------------------
// proj (layer 1), split-K8 (one head per z), DENSE normalized att A-operand.
// grid (7,8,8).
// ---------------------------------------------------------------------------
__global__ __launch_bounds__(256) void proj_kernel(
    const float* __restrict__ att,
    const float* __restrict__ projw, float* __restrict__ Pp)
{
    __shared__ float as[16][68], bs[16][68];
    const int tid = threadIdx.x;
    const int m0 = blockIdx.x * 64, n0 = blockIdx.y * 64, sk = blockIdx.z;
    const int kBeg = sk * 64, kEnd = kBeg + 64;
    float acc[4][4] = {};

    auto loadA = [&](int k0, float r[4]) {
        r[0] = r[1] = r[2] = r[3] = 0.f;
        int gm = m0 + (tid >> 2);
        if (gm > 400) return;
        int gk = k0 + (tid & 3) * 4;
        float4 v = *(const float4*)(att + (long)gm * 512 + gk);
        r[0]=v.x; r[1]=v.y; r[2]=v.z; r[3]=v.w;
    };
    auto loadB = [&](int k0, float r[4]) {
        int gk = k0 + (tid >> 4);
        int gn = n0 + (tid & 15) * 4;
        float4 v = *(const float4*)(projw + (long)gk * 512 + gn);
        r[0]=v.x; r[1]=v.y; r[2]=v.z; r[3]=v.w;
    };
    gemm64<false>(kBeg, kEnd, tid, as, bs, acc, loadA, loadB);

    float* C = Pp + (long)sk * PVS;
    const int tx = tid & 15, ty = tid >> 4;
    #pragma unroll
    for (int r = 0; r < 4; ++r) {
        int m = m0 + ty * 4 + r;
        if (m > 400) continue;
        *(float4*)&C[(long)m * 512 + n0 + tx * 4] =
            make_float4(acc[r][0], acc[r][1], acc[r][2], acc[r][3]);
    }
}

// ---------------------------------------------------------------------------
// Per-row split-K reduce + epilogue + LayerNorm. grid 401.
// ---------------------------------------------------------------------------
__global__ __launch_bounds__(256) void rowfuse_kernel(
    const float* __restrict__ P, long slice, int skN, int rowOff,
    const float* __restrict__ bias, int doRelu,
    const float* __restrict__ resid, const float* __restrict__ cls,
    float* __restrict__ h0,
    const float* __restrict__ g, const float* __restrict__ b,
    float* __restrict__ xln)
{
    const int r = blockIdx.x, t = threadIdx.x;
    float v0, v1;
    if (cls && r == 0) {
        v0 = cls[t]; v1 = cls[t + 256];
    } else {
        const float* p = P + (long)(r - rowOff) * DIM;
        v0 = bias[t]; v1 = bias[t + 256];
        for (int k = 0; k < skN; ++k) {
            v0 += p[(long)k * slice + t];
            v1 += p[(long)k * slice + t + 256];
        }
        if (resid) {
            v0 += resid[(long)r * DIM + t];
            v1 += resid[(long)r * DIM + t + 256];
        }
        if (doRelu) { v0 = fmaxf(v0, 0.f); v1 = fmaxf(v1, 0.f); }
    }
    h0[(long)r * DIM + t] = v0;
    h0[(long)r * DIM + t + 256] = v1;

    float s = v0 + v1, sq = v0 * v0 + v1 * v1;
    #pragma unroll
    for (int off = 32; off > 0; off >>= 1) {
        s += __shfl_down(s, off);
        sq += __shfl_down(sq, off);
    }
    __shared__ float ps[4], pq[4];
    int w = t >> 6, lane = t & 63;
    if (lane == 0) { ps[w] = s; pq[w] = sq; }
    __syncthreads();
    float Sm = ps[0] + ps[1] + ps[2] + ps[3];
    float Q = pq[0] + pq[1] + pq[2] + pq[3];
    float mean = Sm * (1.f / DIM);
    float var = Q * (1.f / DIM) - mean * mean;
    float inv = rsqrtf(var + LN_EPS);
    xln[(long)r * DIM + t]       = (v0 - mean) * inv * g[t] + b[t];
    xln[(long)r * DIM + t + 256] = (v1 - mean) * inv * g[t + 256] + b[t + 256];
}

// ---------------------------------------------------------------------------
// CLS flash-decode (layer 2): grid (8 heads, 7 key-chunks of 64).
// q0 inline from xln row 0; K/V from 4 kv split-K partials + bias inline.
// ---------------------------------------------------------------------------
__global__ __launch_bounds__(256) void cls_decode_kernel(
    const float* __restrict__ xln, const float* __restrict__ qkvw,
    const float* __restrict__ Pkv, const float* __restrict__ qkvb,
    const int* __restrict__ pm, const float* __restrict__ pf,
    const float* __restrict__ T,
    float* __restrict__ cms, float* __restrict__ cpv,
    unsigned* __restrict__ cnt)
{
    const int h = blockIdx.x, c = blockIdx.y, tid = threadIdx.x;
    const int kBeg = c * 64;
    __shared__ float q0[64], scraw[64], p[64], red[4][64], rr[2];

    if (h == 0 && c == 0 && tid == 0) *cnt = 0u;   // init for cls_proj

    // q0[d] = sum_k xln[0][k] * Wq[k][h*64+d] + bq[h*64+d]; 4-wave k-split
    {
        int d = tid & 63, w4 = tid >> 6;
        const float* col = qkvw + h * 64 + d;
        float acc = 0.f;
        for (int k = w4 * 128; k < w4 * 128 + 128; ++k)
            acc = fmaf(xln[k], col[(long)k * 1536], acc);
        red[w4][d] = acc;
    }
    __syncthreads();
    if (tid < 64)
        q0[tid] = red[0][tid] + red[1][tid] + red[2][tid] + red[3][tid]
                  + qkvb[h * 64 + tid];
    __syncthreads();

    // scores: key k = tid>>2 (4 lanes/key, 16 dims each), shuffle-reduce
    {
        int k = tid >> 2, q = tid & 3;
        int j = kBeg + k;
        float dot = 0.f;
        if (j < NP) {
            long base = (long)j * 1024 + h * 64 + q * 16;   // K cols 0..512
            #pragma unroll
            for (int d = 0; d < 16; d += 4) {
                float4 x = *(const float4*)(qkvb + 512 + h * 64 + q * 16 + d);
                #pragma unroll
                for (int s = 0; s < 4; ++s) {
                    float4 v = *(const float4*)(Pkv + (long)s * PKS + base + d);
                    x.x += v.x; x.y += v.y; x.z += v.z; x.w += v.w;
                }
                float4 qq = *(const float4*)(q0 + q * 16 + d);
                dot = fmaf(qq.x, x.x, dot);
                dot = fmaf(qq.y, x.y, dot);
                dot = fmaf(qq.z, x.z, dot);
                dot = fmaf(qq.w, x.w, dot);
            }
        }
        dot += __shfl_down(dot, 2);
        dot += __shfl_down(dot, 1);
        if (q == 0) scraw[k] = dot;
    }
    __syncthreads();

    // bias + local softmax on wave 0
    if (tid < 64) {
        int j = kBeg + tid;
        float s;
        if (j < NP) {
            int mm = pm[j];                   // row 0 of pair map
            float fr = pf[j];
            const float* Tt = T + (long)h * TSTRIDE;
            float t0 = Tt[mm], t1 = Tt[mm + 1];
            s = fmaf(scraw[tid], ATT_SCALE, fmaf(fr, t1 - t0, t0));
        } else {
            s = -INFINITY;
        }
        float m = s;
        #pragma unroll
        for (int off = 32; off > 0; off >>= 1)
            m = fmaxf(m, __shfl_xor(m, off));
        float e = (j < NP) ? __expf(s - m) : 0.f;
        float sum = e;
        #pragma unroll
        for (int off = 32; off > 0; off >>= 1)
            sum += __shfl_xor(sum, off);
        p[tid] = e;
        if (tid == 0) { rr[0] = m; rr[1] = sum; }
    }
    __syncthreads();

    // partial PV: d = lane, wave w handles keys k ≡ w (mod 4)
    {
        int w = tid >> 6, d = tid & 63;
        float vb = qkvb[1024 + h * 64 + d];
        float acc = 0.f;
        for (int k = w; k < 64; k += 4) {
            int j = kBeg + k;
            if (j >= NP) break;
            long o = (long)j * 1024 + 512 + h * 64 + d;     // V cols 512..1024
            float v = vb;
            #pragma unroll
            for (int s = 0; s < 4; ++s) v += Pkv[(long)s * PKS + o];
            acc = fmaf(p[k], v, acc);
        }
        red[w][d] = acc;
    }
    __syncthreads();
    if (tid < 64) {
        cpv[((long)h * 7 + c) * 64 + tid] =
            red[0][tid] + red[1][tid] + red[2][tid] + red[3][tid];
        if (tid == 0) {
            cms[(h * 7 + c) * 2 + 0] = rr[0];
            cms[(h * 7 + c) * 2 + 1] = rr[1];
        }
    }
}

// ---------------------------------------------------------------------------
// CLS proj (inlined LSE combine) + last-block fused residual+LN+fc2 -> out.
// grid 8 x 256 thr.
// ---------------------------------------------------------------------------
__global__ __launch_bounds__(256) void cls_proj_kernel(
    const float* __restrict__ cms, const float* __restrict__ cpv,
    const float* __restrict__ projw, const float* __restrict__ projb,
    float* __restrict__ proj0,
    const float* __restrict__ h0,
    const float* __restrict__ g, const float* __restrict__ b,
    const float* __restrict__ fc2w, const float* __restrict__ fc2b,
    float* __restrict__ out, unsigned* __restrict__ cnt)
{
    __shared__ float av[512], red[4][64];
    __shared__ int isLast;
    const int bk = blockIdx.x, tid = threadIdx.x;
    for (int d = tid; d < 512; d += 256) {
        int h = d >> 6, dd = d & 63;
        float M = -INFINITY;
        #pragma unroll
        for (int c = 0; c < 7; ++c)
            M = fmaxf(M, cms[(h * 7 + c) * 2]);
        float Sx = 0.f, acc = 0.f;
        #pragma unroll
        for (int c = 0; c < 7; ++c) {
            float e = __expf(cms[(h * 7 + c) * 2] - M);
            Sx += cms[(h * 7 + c) * 2 + 1] * e;
            acc += cpv[((long)h * 7 + c) * 64 + dd] * e;
        }
        av[d] = acc / Sx;
    }
    __syncthreads();
    int gg = tid >> 6, n = bk * 64 + (tid & 63);
    float acc = 0.f;
    for (int k = gg * 128; k < gg * 128 + 128; ++k)
        acc = fmaf(av[k], projw[(long)k * 512 + n], acc);
    red[gg][tid & 63] = acc;
    __syncthreads();
    if (tid < 64)
        proj0[bk * 64 + tid] = red[0][tid] + red[1][tid] + red[2][tid]
                               + red[3][tid] + projb[bk * 64 + tid];

    // last-block: residual + LN + fc2 -> out
    __threadfence();
    if (tid == 0) isLast = (atomicAdd(cnt, 1u) == 7u);
    __syncthreads();
    if (!isLast) return;
    __threadfence();

    const int t = tid;
    float v0 = h0[t] + proj0[t];
    float v1 = h0[t + 256] + proj0[t + 256];
    float s = v0 + v1, sq = v0 * v0 + v1 * v1;
    #pragma unroll
    for (int off = 32; off > 0; off >>= 1) {
        s += __shfl_down(s, off);
        sq += __shfl_down(sq, off);
    }
    __shared__ float ps[4], pq[4], pc0[4], pc1[4];
    int w = t >> 6, lane = t & 63;
    if (lane == 0) { ps[w] = s; pq[w] = sq; }
    __syncthreads();
    float Sm = ps[0] + ps[1] + ps[2] + ps[3];
    float Q = pq[0] + pq[1] + pq[2] + pq[3];
    float mean = Sm * (1.f / DIM);
    float var = Q * (1.f / DIM) - mean * mean;
    float inv = rsqrtf(var + LN_EPS);
    float n0 = (v0 - mean) * inv * g[t] + b[t];
    float n1 = (v1 - mean) * inv * g[t + 256] + b[t + 256];
    float c0 = n0 * fc2w[t * 2]     + n1 * fc2w[(t + 256) * 2];
    float c1 = n0 * fc2w[t * 2 + 1] + n1 * fc2w[(t + 256) * 2 + 1];
    #pragma unroll
    for (int off = 32; off > 0; off >>= 1) {
        c0 += __shfl_down(c0, off);
        c1 += __shfl_down(c1, off);
    }
    if (lane == 0) { pc0[w] = c0; pc1[w] = c1; }
    __syncthreads();
    if (t == 0) {
        out[0] = pc0[0] + pc0[1] + pc0[2] + pc0[3] + fc2b[0];
        out[1] = pc1[0] + pc1[1] + pc1[2] + pc1[3] + fc2b[1];
    }
}

// ---------------------------------------------------------------------------
// Mega init: [0,224) fc1 split-K16 64x256 tiles -> Pp; [224,354) CPB angle
// tables; [354,983) pair -> (angle idx, frac).
// ---------------------------------------------------------------------------
template<typename LA, typename LB>
__device__ __forceinline__ void gemm256(
    int kBeg, int kEnd, int tid,
    float (*as)[68], float (*bs)[260], float (&acc)[4][4][4],
    LA&& loadA, LB&& loadB)
{
    float aR[4], bR[4][4];
    loadA(kBeg, aR);
    loadB(kBeg, bR);
    for (int k0 = kBeg; k0 < kEnd; k0 += 16) {
        const int arow = tid >> 2, aq = tid & 3;
        as[aq * 4 + 0][arow] = aR[0];
        as[aq * 4 + 1][arow] = aR[1];
        as[aq * 4 + 2][arow] = aR[2];
        as[aq * 4 + 3][arow] = aR[3];
        {
            const int brow = tid >> 4, bcol = (tid & 15) * 4;
            #pragma unroll
            for (int j = 0; j < 4; ++j)
                *(float4*)&bs[brow][bcol + 64 * j] =
                    make_float4(bR[j][0], bR[j][1], bR[j][2], bR[j][3]);
        }
        __syncthreads();
        float nA[4] = {0.f,0.f,0.f,0.f};
        float nB[4][4] = {};
        if (k0 + 16 < kEnd) { loadA(k0 + 16, nA); loadB(k0 + 16, nB); }
        const int tx = tid & 15, ty = tid >> 4;
        #pragma unroll
        for (int kk = 0; kk < 16; ++kk) {
            float4 a4 = *(const float4*)&as[kk][ty * 4];
            float av[4] = {a4.x, a4.y, a4.z, a4.w};
            #pragma unroll
            for (int j = 0; j < 4; ++j) {
                float4 b4 = *(const float4*)&bs[kk][tx * 4 + 64 * j];
                float bv[4] = {b4.x, b4.y, b4.z, b4.w};
                #pragma unroll
                for (int r = 0; r < 4; ++r)
                    #pragma unroll
                    for (int c = 0; c < 4; ++c)
                        acc[r][j][c] = fmaf(av[r], bv[c], acc[r][j][c]);
            }
        }
        __syncthreads();
        #pragma unroll
        for (int i = 0; i < 4; ++i) aR[i] = nA[i];
        #pragma unroll
        for (int j = 0; j < 4; ++j)
            #pragma unroll
            for (int i = 0; i < 4; ++i) bR[j][i] = nB[j][i];
    }
}

__global__ __launch_bounds__(256) void mega_kernel(
    const float* __restrict__ hin, const float* __restrict__ fc1_w,
    const float* __restrict__ w1_0, const float* __restrict__ b1_0,
    const float* __restrict__ w2_0, const float* __restrict__ b2_0,
    const float* __restrict__ w1_1, const float* __restrict__ b1_1,
    const float* __restrict__ w2_1, const float* __restrict__ b2_1,
    const float* __restrict__ coords,
    float* __restrict__ Pp, float* __restrict__ T,
    int* __restrict__ pm, float* __restrict__ pf)
{
    __shared__ float smem[5248];
    float (*as)[68]  = (float(*)[68])smem;
    float (*bs)[260] = (float(*)[260])(smem + 1088);
    float (*red)[64][8] = (float(*)[64][8])smem;
    const int bid = blockIdx.x, tid = threadIdx.x;

    if (bid < 224) {
        int sk = bid / 14, rem = bid % 14;
        int m0 = (rem % 7) * 64, n0 = (rem / 7) * 256;
        int kBeg = sk * 64, kEnd = kBeg + 64;   // 16 x 64 = full K=1024
        float acc[4][4][4] = {};
        auto loadA = [&](int k0, float r[4]) {
            r[0]=r[1]=r[2]=r[3]=0.f;
            int gm = m0 + (tid >> 2);
            if (gm >= 400) return;
            int gk = k0 + (tid & 3) * 4;
            float4 v = *(const float4*)(hin + (long)gm * 1024 + gk);
            r[0]=v.x; r[1]=v.y; r[2]=v.z; r[3]=v.w;
        };
        auto loadB = [&](int k0, float r[4][4]) {
            int gk = k0 + (tid >> 4);
            const float* p = fc1_w + (long)gk * 512 + n0 + (tid & 15) * 4;
            #pragma unroll
            for (int j = 0; j < 4; ++j) {
                float4 v = *(const float4*)(p + 64 * j);
                r[j][0]=v.x; r[j][1]=v.y; r[j][2]=v.z; r[j][3]=v.w;
            }
        };
        gemm256(kBeg, kEnd, tid, as, bs, acc, loadA, loadB);
        float* C = Pp + (long)sk * PVS;
        const int tx = tid & 15, ty = tid >> 4;
        #pragma unroll
        for (int r = 0; r < 4; ++r) {
            int m = m0 + ty * 4 + r;
            if (m >= 400) continue;
            #pragma unroll
            for (int j = 0; j < 4; ++j)
                *(float4*)&C[(long)m * 512 + n0 + tx * 4 + 64 * j] =
                    make_float4(acc[r][j][0], acc[r][j][1],
                                acc[r][j][2], acc[r][j][3]);
        }
    } else if (bid < 354) {
        int tb = bid - 224;
        int z = tb / 65, ab = tb % 65;
        const float* w1 = z ? w1_1 : w1_0;
        const float* b1 = z ? b1_1 : b1_0;
        const float* w2 = z ? w2_1 : w2_0;
        const float* b2 = z ? b2_1 : b2_0;
        const int lane = tid & 63, wv = tid >> 6;
        float ca = 0.f, sa = 0.f;
        if (ab != 64) {
            float th = fmaf((float)(ab * 64 + lane),
                            (float)(2.0 * M_PI / CPB_M), -(float)M_PI);
            sincosf(th, &sa, &ca);
        } else if (lane == 0) {
            sincosf((float)M_PI, &sa, &ca);  // wrap row; lanes>0 zero-vec
        }
        float a8[8] = {};
        const int kbeg = wv * 128;
        #pragma unroll 4
        for (int k = kbeg; k < kbeg + 128; ++k) {
            float hk = fmaxf(fmaf(ca, w1[k],
                                  fmaf(sa, w1[512 + k], b1[k])), 0.f);
            #pragma unroll
            for (int h2 = 0; h2 < 8; ++h2)
                a8[h2] = fmaf(hk, w2[k * 8 + h2], a8[h2]);
        }
        #pragma unroll
        for (int h2 = 0; h2 < 8; ++h2) red[wv][lane][h2] = a8[h2];
        __syncthreads();
        if (tid < 64) {
            int aidx = ab * 64 + tid;
            if (aidx <= CPB_M + 1) {
                #pragma unroll
                for (int h2 = 0; h2 < 8; ++h2)
                    T[(long)(z * 8 + h2) * TSTRIDE + aidx] =
                        red[0][tid][h2] + red[1][tid][h2] +
                        red[2][tid][h2] + red[3][tid][h2] + b2[h2];
            }
        }
    } else {
        int p = (bid - 354) * 256 + tid;
        if (p < NP * NP) {
            int i = p / NP, j = p - i * NP;
            float xi = (i == 0) ? 0.f : coords[(i - 1) * 2];
            float yi = (i == 0) ? 0.f : coords[(i - 1) * 2 + 1];
            float xj = (j == 0) ? 0.f : coords[(j - 1) * 2];
            float yj = (j == 0) ? 0.f : coords[(j - 1) * 2 + 1];
            float rx = xi - xj, ry = yi - yj;
            int mm; float fr;
            if (rx == 0.f && ry == 0.f) {
                mm = CPB_M + 1; fr = 0.f;
            } else {
                float x = (atan2f(ry, rx) + 3.14159265358979f)
                          * (float)(CPB_M / (2.0 * M_PI));
                int mi = (int)x;
                fr = x - (float)mi;
                mm = (mi >= CPB_M) ? mi - CPB_M : mi;
            }
            pm[i * 416 + j] = mm;
            pf[i * 416 + j] = fr;
        }
    }
}

// ---------------------------------------------------------------------------
extern "C" void kernel_launch(void* const* d_in, const int* in_sizes, int n_in,
                              void* d_out, int out_size, void* d_ws, size_t ws_size,
                              hipStream_t stream)
{
    const float* coords = (const float*)d_in[1];
    float* ws = (float*)d_ws;
    float* h0   = ws;                    ws += 401L * 512;
    float* xln  = ws;                    ws += 401L * 512;
    float* att  = ws;                    ws += 401L * 512;
    float* PO   = ws;                    ws += 7L * PVS;   // flash O-partials
    float* T    = ws;                    ws += 16L * TSTRIDE;
    int*   pm   = (int*)ws;              ws += 401L * 416;
    float* pf   = ws;                    ws += 401L * 416;
    float* Pq   = ws;                    ws += 4L * PKS;   // >= 2*PQS; also l2-kv
    float* Pp   = ws;                    ws += 16L * PVS;  // fc1(K16)/proj(K8)
    float* proj0 = ws;                   ws += 512;
    float* cms  = ws;                    ws += 8L * 7 * 2;
    float* cpv  = ws;                    ws += 8L * 7 * 64;
    float* Pml  = ws;                    ws += 8L * 401 * 7 * 2;
    unsigned* cnt = (unsigned*)ws;       ws += 16;

    // phase 0: fc1 (split-K16, 64x256) + CPB angle tables + pair->angle map
    mega_kernel<<<983, 256, 0, stream>>>(
        (const float*)d_in[0], (const float*)d_in[2],
        (const float*)d_in[7],  (const float*)d_in[8],
        (const float*)d_in[9],  (const float*)d_in[10],
        (const float*)d_in[17], (const float*)d_in[18],
        (const float*)d_in[19], (const float*)d_in[20],
        coords, Pp, T, pm, pf);

    // fc1 reduce + relu + cls + LN(l1) -> h0, xln
    rowfuse_kernel<<<401, 256, 0, stream>>>(
        Pp, PVS, 16, 1, (const float*)d_in[3], 1, nullptr,
        (const float*)d_in[4], h0,
        (const float*)d_in[5], (const float*)d_in[6], xln);

    // -------- layer 1: split-K2 64x128 qkv, flash folds 2 slices ------
    gemm_split128_kernel<<<dim3(7, 12, 2), 256, 0, stream>>>(
        xln, 512, (const float*)d_in[11], 1536, Pq, 1536, PQS,
        401, 512, 2);
    flash_kernel<<<dim3(7, 7, 8), 256, 0, stream>>>(
        Pq, (const float*)d_in[12], pm, pf, T, PO, Pml);
    combine_kernel<<<401, 256, 0, stream>>>(PO, Pml, att);
    proj_kernel<<<dim3(7, 8, 8), 256, 0, stream>>>(
        att, (const float*)d_in[13], Pp);
    rowfuse_kernel<<<401, 256, 0, stream>>>(
        Pp, PVS, 8, 0, (const float*)d_in[14], 0, h0, nullptr, h0,
        (const float*)d_in[15], (const float*)d_in[16], xln);

    // -------- layer 2: split-K4 64x64 K,V, CLS flash-decode ----------
    gemm_split_kernel<<<dim3(7, 16, 4), 256, 0, stream>>>(
        xln, 512, (const float*)d_in[21] + 512, 1536, Pq, 1024, PKS,
        401, 512, 4);
    cls_decode_kernel<<<dim3(8, 7), 256, 0, stream>>>(
        xln, (const float*)d_in[21], Pq, (const float*)d_in[22],
        pm, pf, T + 8L * TSTRIDE, cms, cpv, cnt);
    cls_proj_kernel<<<8, 256, 0, stream>>>(
        cms, cpv, (const float*)d_in[23], (const float*)d_in[24], proj0,
        h0, (const float*)d_in[25], (const float*)d_in[26],
        (const float*)d_in[27], (const float*)d_in[28], (float*)d_out, cnt);
}